// Round 1
// baseline (433.921 us; speedup 1.0000x reference)
//
#include <hip/hip_runtime.h>

// MultiStepLIF, decay_input=False, hard reset to 0, tau=2, thresh=1.
// x: [T=4, B*N] fp32. out: spikes same shape, fp32 (0.0 or 1.0).
// Recurrence per neuron: v = 0.5*v + x_t ; s = (v >= 1) ; v = s ? 0 : v.
// Streaming kernel: 1 thread = 4 neurons (float4), T unrolled, v in registers.

#define T_STEPS 4

__global__ __launch_bounds__(256) void lif_spike_kernel(
    const float4* __restrict__ x, float4* __restrict__ out, int n4)
{
    int i = blockIdx.x * blockDim.x + threadIdx.x;
    if (i >= n4) return;

    float4 v = make_float4(0.f, 0.f, 0.f, 0.f);

#pragma unroll
    for (int t = 0; t < T_STEPS; ++t) {
        const float4 xt = x[(size_t)t * n4 + i];
        float4 s;

        v.x = 0.5f * v.x + xt.x;
        v.y = 0.5f * v.y + xt.y;
        v.z = 0.5f * v.z + xt.z;
        v.w = 0.5f * v.w + xt.w;

        s.x = (v.x >= 1.0f) ? 1.0f : 0.0f;
        s.y = (v.y >= 1.0f) ? 1.0f : 0.0f;
        s.z = (v.z >= 1.0f) ? 1.0f : 0.0f;
        s.w = (v.w >= 1.0f) ? 1.0f : 0.0f;

        v.x = (v.x >= 1.0f) ? 0.0f : v.x;
        v.y = (v.y >= 1.0f) ? 0.0f : v.y;
        v.z = (v.z >= 1.0f) ? 0.0f : v.z;
        v.w = (v.w >= 1.0f) ? 0.0f : v.w;

        out[(size_t)t * n4 + i] = s;
    }
}

extern "C" void kernel_launch(void* const* d_in, const int* in_sizes, int n_in,
                              void* d_out, int out_size, void* d_ws, size_t ws_size,
                              hipStream_t stream)
{
    const float* x = (const float*)d_in[0];
    float* out = (float*)d_out;

    const int n_total = in_sizes[0];          // T * B * N = 67,108,864
    const int n_per_t = n_total / T_STEPS;    // 16,777,216 (divisible by 4)
    const int n4 = n_per_t / 4;               // 4,194,304 float4 per timestep

    const int block = 256;
    const int grid = (n4 + block - 1) / block;

    lif_spike_kernel<<<grid, block, 0, stream>>>(
        (const float4*)x, (float4*)out, n4);
}

// Round 3
// 429.517 us; speedup vs baseline: 1.0103x; 1.0103x over previous
//
#include <hip/hip_runtime.h>

// MultiStepLIF, decay_input=False, hard reset to 0, tau=2, thresh=1.
// x: [T=4, B*N] fp32. out: spikes same shape, fp32 (0.0 or 1.0).
// Per neuron: v = 0.5*v + x_t ; s = (v >= 1) ; v = s ? 0 : v.
//
// Streaming, one-touch data (512 MiB total > 256 MiB L3):
//  - 1 thread = 8 neurons (2x vec4), ALL 8 loads issued up front (128 B
//    in flight per thread) for maximum memory-level parallelism.
//  - nontemporal loads/stores: no reuse, skip cache allocation.
//  - NOTE: use Clang ext_vector_type, not HIP float4 — the nontemporal
//    builtins reject class types (HIP_vector_type).

#define T_STEPS 4

typedef float vf4 __attribute__((ext_vector_type(4)));

__device__ __forceinline__ void lif_step(vf4& v, const vf4 xt, vf4& s)
{
    v = 0.5f * v + xt;
    s.x = (v.x >= 1.0f) ? 1.0f : 0.0f;
    s.y = (v.y >= 1.0f) ? 1.0f : 0.0f;
    s.z = (v.z >= 1.0f) ? 1.0f : 0.0f;
    s.w = (v.w >= 1.0f) ? 1.0f : 0.0f;

    v.x = (v.x >= 1.0f) ? 0.0f : v.x;
    v.y = (v.y >= 1.0f) ? 0.0f : v.y;
    v.z = (v.z >= 1.0f) ? 0.0f : v.z;
    v.w = (v.w >= 1.0f) ? 0.0f : v.w;
}

__global__ __launch_bounds__(256) void lif_spike_kernel(
    const vf4* __restrict__ x, vf4* __restrict__ out, int n4)
{
    const size_t i = 2 * ((size_t)blockIdx.x * blockDim.x + threadIdx.x);
    if (i >= (size_t)n4) return;   // n4 is even; i+1 in bounds when i < n4

    // Hoist all T*2 loads: 8 global_load_dwordx4 in flight per thread.
    vf4 xt[T_STEPS][2];
#pragma unroll
    for (int t = 0; t < T_STEPS; ++t) {
        xt[t][0] = __builtin_nontemporal_load(&x[(size_t)t * n4 + i]);
        xt[t][1] = __builtin_nontemporal_load(&x[(size_t)t * n4 + i + 1]);
    }

    vf4 v0 = (vf4)(0.f);
    vf4 v1 = (vf4)(0.f);

#pragma unroll
    for (int t = 0; t < T_STEPS; ++t) {
        vf4 s0, s1;
        lif_step(v0, xt[t][0], s0);
        lif_step(v1, xt[t][1], s1);
        __builtin_nontemporal_store(s0, &out[(size_t)t * n4 + i]);
        __builtin_nontemporal_store(s1, &out[(size_t)t * n4 + i + 1]);
    }
}

extern "C" void kernel_launch(void* const* d_in, const int* in_sizes, int n_in,
                              void* d_out, int out_size, void* d_ws, size_t ws_size,
                              hipStream_t stream)
{
    const float* x = (const float*)d_in[0];
    float* out = (float*)d_out;

    const int n_total = in_sizes[0];          // T * B * N = 67,108,864
    const int n_per_t = n_total / T_STEPS;    // 16,777,216
    const int n4 = n_per_t / 4;               // 4,194,304 vec4 per timestep

    const int block = 256;
    const int threads_needed = n4 / 2;        // 2 vec4 per thread
    const int grid = (threads_needed + block - 1) / block;

    lif_spike_kernel<<<grid, block, 0, stream>>>(
        (const vf4*)x, (vf4*)out, n4);
}

// Round 4
// 425.425 us; speedup vs baseline: 1.0200x; 1.0096x over previous
//
#include <hip/hip_runtime.h>

// MultiStepLIF, decay_input=False, hard reset to 0, tau=2, thresh=1.
// x: [T=4, B*N] fp32. out: spikes same shape, fp32 (0.0 or 1.0).
// Per neuron: v = 0.5*v + x_t ; s = (v >= 1) ; v = s ? 0 : v.
//
// Pure one-touch stream (512 MiB total): HBM-bound, floor ~82 us @ 6.3 TB/s.
// Grid-stride form (m13 copy-bench pattern): 4096 blocks x 256 threads,
// exactly 4 iterations/thread over n4 = 4,194,304 vec4 neurons. Independent
// iterations let the compiler software-pipeline loads of iter k+1 past the
// stores of iter k. Unit-stride per instruction; nontemporal (one-touch).

#define T_STEPS 4

typedef float vf4 __attribute__((ext_vector_type(4)));

__device__ __forceinline__ vf4 lif_step(vf4& v, const vf4 xt)
{
    v = 0.5f * v + xt;
    vf4 s;
    s.x = (v.x >= 1.0f) ? 1.0f : 0.0f;
    s.y = (v.y >= 1.0f) ? 1.0f : 0.0f;
    s.z = (v.z >= 1.0f) ? 1.0f : 0.0f;
    s.w = (v.w >= 1.0f) ? 1.0f : 0.0f;
    v.x = (v.x >= 1.0f) ? 0.0f : v.x;
    v.y = (v.y >= 1.0f) ? 0.0f : v.y;
    v.z = (v.z >= 1.0f) ? 0.0f : v.z;
    v.w = (v.w >= 1.0f) ? 0.0f : v.w;
    return s;
}

__global__ __launch_bounds__(256) void lif_spike_kernel(
    const vf4* __restrict__ x, vf4* __restrict__ out, unsigned n4)
{
    const unsigned stride = gridDim.x * blockDim.x;
    for (unsigned i = blockIdx.x * blockDim.x + threadIdx.x; i < n4; i += stride) {
        // 4 independent loads in flight (t-major planes, 64 MiB apart;
        // each instruction unit-stride across lanes).
        const vf4 x0 = __builtin_nontemporal_load(&x[(size_t)0 * n4 + i]);
        const vf4 x1 = __builtin_nontemporal_load(&x[(size_t)1 * n4 + i]);
        const vf4 x2 = __builtin_nontemporal_load(&x[(size_t)2 * n4 + i]);
        const vf4 x3 = __builtin_nontemporal_load(&x[(size_t)3 * n4 + i]);

        vf4 v = (vf4)(0.f);
        const vf4 s0 = lif_step(v, x0);
        const vf4 s1 = lif_step(v, x1);
        const vf4 s2 = lif_step(v, x2);
        const vf4 s3 = lif_step(v, x3);

        __builtin_nontemporal_store(s0, &out[(size_t)0 * n4 + i]);
        __builtin_nontemporal_store(s1, &out[(size_t)1 * n4 + i]);
        __builtin_nontemporal_store(s2, &out[(size_t)2 * n4 + i]);
        __builtin_nontemporal_store(s3, &out[(size_t)3 * n4 + i]);
    }
}

extern "C" void kernel_launch(void* const* d_in, const int* in_sizes, int n_in,
                              void* d_out, int out_size, void* d_ws, size_t ws_size,
                              hipStream_t stream)
{
    const float* x = (const float*)d_in[0];
    float* out = (float*)d_out;

    const int n_total = in_sizes[0];          // T * B * N = 67,108,864
    const unsigned n4 = (unsigned)(n_total / T_STEPS / 4);  // 4,194,304

    const int block = 256;
    const int grid = 4096;   // 16 WGs/CU; 4 grid-stride iterations/thread

    lif_spike_kernel<<<grid, block, 0, stream>>>(
        (const vf4*)x, (vf4*)out, n4);
}